// Round 16
// baseline (369.104 us; speedup 1.0000x reference)
//
#include <hip/hip_runtime.h>

#define NN   4096   // nodes
#define ED   64     // embed dim
#define DIN  256    // in_dim
#define DOUT 256    // out_dim
#define NB   32     // batch

typedef __attribute__((ext_vector_type(8)))  short bf16x8;
typedef __attribute__((ext_vector_type(4)))  float f32x4;
typedef __attribute__((ext_vector_type(16))) float f32x16;

__device__ __forceinline__ unsigned short f2bf(float f) {
    union { float f; unsigned u; } v; v.f = f;
    unsigned r = v.u + 0x7FFF + ((v.u >> 16) & 1);   // round-to-nearest-even
    return (unsigned short)(r >> 16);
}
__device__ __forceinline__ float bf2f(unsigned short s) {
    union { unsigned u; float f; } v; v.u = ((unsigned)s) << 16;
    return v.f;
}

// async global->LDS, 16B per lane; lds dst must be wave-uniform (lane*16 implicit)
#define GLDS16(g, l) __builtin_amdgcn_global_load_lds( \
    (const __attribute__((address_space(1))) void*)(g), \
    (__attribute__((address_space(3))) void*)(l), 16, 0, 0)

// ---------------- K1: Ebf = bf16(emb[node_ids]); Z = 0 ----------------
__global__ void k_gather(const float* __restrict__ emb, const int* __restrict__ ids,
                         unsigned short* __restrict__ Ebf, float* __restrict__ Z) {
    int n = blockIdx.x;
    int e = threadIdx.x;          // 64 threads
    int id = ids[n];
    id = id < 0 ? 0 : (id >= NN ? NN - 1 : id);
    Ebf[(size_t)n * ED + e] = f2bf(emb[(size_t)id * ED + e]);
    if (e == 0) Z[n] = 0.0f;      // zero row-sum accumulator every launch
}

// ---------------- K2: P = exp(relu(E E^T)) bf16 via MFMA; Z[row] += row-sums ----
// 128x128 tile/block, 4 waves (2x2), K=64 one-shot. Fragment-order LDS staging
// ([rowblk][ks][1KB], ds_read = base + lane*16, conflict-free by construction).
__global__ __launch_bounds__(256) void k_logits(const unsigned short* __restrict__ Ebf,
                                                unsigned short* __restrict__ P,
                                                float* __restrict__ Z) {
    __shared__ __align__(16) char sm[32768];      // A 16KB + B 16KB
    const int tid = threadIdx.x;
    const int lane = tid & 63, wid = tid >> 6;    // 4 waves
    const int fr = lane & 15, fq = lane >> 4;
    const int wr = wid >> 1, wc = wid & 1;        // wave tile 64x64
    const int rb = blockIdx.x, cb = blockIdx.y;
    const char* Ep = (const char*)Ebf;            // row stride 128 B

    // stage A rows rb*128.. and B rows cb*128.., frag-order: lane l -> row l&15,
    // k-bytes ks*64 + (l>>4)*16. 8 gload_lds per wave.
    #pragma unroll
    for (int i = 0; i < 2; ++i) {
        int arb = wid * 2 + i;
        #pragma unroll
        for (int ks = 0; ks < 2; ++ks) {
            GLDS16(Ep + (size_t)(rb * 128 + arb * 16 + fr) * 128 + ks * 64 + fq * 16,
                   sm + arb * 2048 + ks * 1024);
            GLDS16(Ep + (size_t)(cb * 128 + arb * 16 + fr) * 128 + ks * 64 + fq * 16,
                   sm + 16384 + arb * 2048 + ks * 1024);
        }
    }
    asm volatile("s_waitcnt vmcnt(0)" ::: "memory");
    __syncthreads();

    bf16x8 Afr[4][2], Bfr[4][2];
    #pragma unroll
    for (int mi = 0; mi < 4; ++mi)
        #pragma unroll
        for (int ks = 0; ks < 2; ++ks) {
            Afr[mi][ks] = *(const bf16x8*)(sm + (wr * 4 + mi) * 2048 + ks * 1024 + lane * 16);
            Bfr[mi][ks] = *(const bf16x8*)(sm + 16384 + (wc * 4 + mi) * 2048 + ks * 1024 + lane * 16);
        }

    f32x4 acc[4][4];
    #pragma unroll
    for (int i = 0; i < 4; ++i)
        #pragma unroll
        for (int j = 0; j < 4; ++j) acc[i][j] = (f32x4){0.f, 0.f, 0.f, 0.f};
    #pragma unroll
    for (int ks = 0; ks < 2; ++ks)
        #pragma unroll
        for (int mi = 0; mi < 4; ++mi)
            #pragma unroll
            for (int ni = 0; ni < 4; ++ni)
                acc[mi][ni] = __builtin_amdgcn_mfma_f32_16x16x32_bf16(
                    Afr[mi][ks], Bfr[ni][ks], acc[mi][ni], 0, 0, 0);

    // exp(relu(.)) -> P bf16; accumulate row sums
    float rs[4][4];
    #pragma unroll
    for (int mi = 0; mi < 4; ++mi)
        #pragma unroll
        for (int r = 0; r < 4; ++r) rs[mi][r] = 0.f;

    #pragma unroll
    for (int mi = 0; mi < 4; ++mi)
        #pragma unroll
        for (int ni = 0; ni < 4; ++ni) {
            int col = cb * 128 + wc * 64 + ni * 16 + fr;
            #pragma unroll
            for (int r = 0; r < 4; ++r) {
                int row = rb * 128 + wr * 64 + mi * 16 + fq * 4 + r;
                float v = __expf(fmaxf(acc[mi][ni][r], 0.f));
                rs[mi][r] += v;
                P[(size_t)row * NN + col] = f2bf(v);
            }
        }
    #pragma unroll
    for (int mi = 0; mi < 4; ++mi)
        #pragma unroll
        for (int r = 0; r < 4; ++r) {
            float s = rs[mi][r];
            #pragma unroll
            for (int off = 1; off < 16; off <<= 1) s += __shfl_xor(s, off);
            if (fr == 0)
                atomicAdd(&Z[rb * 128 + wr * 64 + mi * 16 + fq * 4 + r], s);
        }
}

// ---------------- K3: WT[m][k] = bf16(W[k][m]) ----------------
__global__ void k_wt(const float* __restrict__ W, unsigned short* __restrict__ WT) {
    int m = blockIdx.x;    // dout
    int k = threadIdx.x;   // din
    WT[(size_t)m * DIN + k] = f2bf(W[(size_t)k * DOUT + m]);
}

// ---------------- K4: yT[b][dout][node] = bf16( (x@W)^T ) ----------------
__global__ __launch_bounds__(256) void k_y(const unsigned short* __restrict__ WT,
                                           const float* __restrict__ x,
                                           unsigned short* __restrict__ yT) {
    __shared__ __align__(16) short As[128 * 32];
    __shared__ __align__(16) short Bs[128 * 32];
    const int tid = threadIdx.x;
    const int lane = tid & 63, w = tid >> 6;
    const int wr = (w >> 1) * 64, wc = (w & 1) * 64;
    const int fr = lane & 15, fq = lane >> 4;
    const int m0 = blockIdx.x * 128;   // dout tile
    const int n0 = blockIdx.y * 128;   // node tile
    const int b  = blockIdx.z;
    const float* xb = x + (size_t)b * NN * DIN;
    const int brow = tid >> 1, bh = (tid & 1) * 16;   // B staging: row, k-half

    f32x4 acc[4][4];
    #pragma unroll
    for (int i = 0; i < 4; ++i)
        #pragma unroll
        for (int j = 0; j < 4; ++j) acc[i][j] = (f32x4){0.f, 0.f, 0.f, 0.f};

    for (int k0 = 0; k0 < DIN; k0 += 32) {
        __syncthreads();
        #pragma unroll
        for (int i = 0; i < 2; ++i) {
            int idx = (w * 2 + i) * 512 + lane * 8;
            int row = idx >> 5, kk = idx & 31;
            GLDS16(WT + (size_t)(m0 + row) * DIN + k0 + kk, &As[(w * 2 + i) * 512]);
        }
        float fv[16];
        *(float4*)&fv[0]  = *(const float4*)&xb[(size_t)(n0 + brow) * DIN + k0 + bh + 0];
        *(float4*)&fv[4]  = *(const float4*)&xb[(size_t)(n0 + brow) * DIN + k0 + bh + 4];
        *(float4*)&fv[8]  = *(const float4*)&xb[(size_t)(n0 + brow) * DIN + k0 + bh + 8];
        *(float4*)&fv[12] = *(const float4*)&xb[(size_t)(n0 + brow) * DIN + k0 + bh + 12];
        unsigned u[8];
        #pragma unroll
        for (int j = 0; j < 8; ++j)
            u[j] = (unsigned)f2bf(fv[2 * j]) | ((unsigned)f2bf(fv[2 * j + 1]) << 16);
        *(uint4*)&Bs[brow * 32 + bh]     = make_uint4(u[0], u[1], u[2], u[3]);
        *(uint4*)&Bs[brow * 32 + bh + 8] = make_uint4(u[4], u[5], u[6], u[7]);
        __syncthreads();

        bf16x8 a[4], bb[4];
        #pragma unroll
        for (int mi = 0; mi < 4; ++mi)
            a[mi] = *(const bf16x8*)&As[(wr + mi * 16 + fr) * 32 + fq * 8];
        #pragma unroll
        for (int ni = 0; ni < 4; ++ni)
            bb[ni] = *(const bf16x8*)&Bs[(wc + ni * 16 + fr) * 32 + fq * 8];
        #pragma unroll
        for (int mi = 0; mi < 4; ++mi)
            #pragma unroll
            for (int ni = 0; ni < 4; ++ni)
                acc[mi][ni] = __builtin_amdgcn_mfma_f32_16x16x32_bf16(
                    a[mi], bb[ni], acc[mi][ni], 0, 0, 0);
    }

    unsigned short* yb = yT + (size_t)b * DOUT * NN;
    #pragma unroll
    for (int mi = 0; mi < 4; ++mi)
        #pragma unroll
        for (int ni = 0; ni < 4; ++ni)
            #pragma unroll
            for (int r = 0; r < 4; ++r) {
                int row = m0 + wr + mi * 16 + fq * 4 + r;   // dout
                int col = n0 + wc + ni * 16 + fr;           // node
                yb[(size_t)row * NN + col] = f2bf(acc[mi][ni][r]);
            }
}

// ---------------- K5: big GEMM, 32x32x16 MFMA, R9 4-phase skeleton ----
// C[4096 x 8192] = P[4096 x 4096] @ Y[4096 x 8192], Y^T = yT flat [8192][4096].
// out[b][node][dout] = relu(C/Z + bias). 8 waves (2M x 4N), wave 128x64.
// LDS per buffer: A,B each [ks(4)][rowblk(8)][1KB frag] (32KB); fragments are
// contiguous 1KB chunks -> ds_read = base + lane*16, conflict-free, no swizzle.
// mfma_f32_32x32x16_bf16: same frag bytes, 2x FLOP/instr vs 16x16x32.
__global__ __launch_bounds__(512, 2) void k_gcn(const unsigned short* __restrict__ adj,
                                                const unsigned short* __restrict__ yT,
                                                const float* __restrict__ bias,
                                                const float* __restrict__ Z,
                                                float* __restrict__ out) {
    __shared__ __align__(16) char smem[131072];   // 2 bufs x (A 32K + B 32K)

    const int tid  = threadIdx.x;
    const int lane = tid & 63, wid = tid >> 6;    // 8 waves
    const int l31 = lane & 31, lhi = lane >> 5;
    const int wr = wid >> 2, wc = wid & 3;        // 2 M-waves x 4 N-waves
    const int m0 = blockIdx.x * 256;              // node tile base
    const int by = blockIdx.y;                    // batch

    const char* Apanel = (const char*)(adj + (size_t)m0 * NN);          // row stride 8192 B
    const char* Bpanel = (const char*)(yT + (size_t)by * DOUT * NN);    // rows = dout 0..255

    // stage one K-half (2 ks-steps) of A or B: 2 gload_lds/wave.
    // Fragment (rowblk=wid, ks): lane l -> row wid*32+(l&31), k-bytes ks*32+(l>>5)*16;
    // LDS dst = buf + ks*8192 + wid*1024 (+ lane*16 implicit) -> frag-order layout.
    #define STAGE_A_HALF(T, H, buf)                                              \
        { _Pragma("unroll")                                                      \
          for (int i = 0; i < 2; ++i) {                                          \
              int ks = (H) * 2 + i;                                              \
              GLDS16(Apanel + (size_t)(wid * 32 + l31) * 8192 + (T) * 128        \
                            + ks * 32 + lhi * 16,                                \
                     (buf) + ks * 8192 + wid * 1024);                            \
          } }
    #define STAGE_B_HALF(T, H, buf)                                              \
        { _Pragma("unroll")                                                      \
          for (int i = 0; i < 2; ++i) {                                          \
              int ks = (H) * 2 + i;                                              \
              GLDS16(Bpanel + (size_t)(wid * 32 + l31) * 8192 + (T) * 128        \
                            + ks * 32 + lhi * 16,                                \
                     (buf) + ks * 8192 + wid * 1024);                            \
          } }

    // prologue: t0 H0, t0 H1, t1 H0 (12 loads/wave; FIFO matches steady state)
    STAGE_A_HALF(0, 0, smem);
    STAGE_B_HALF(0, 0, smem + 32768);
    STAGE_A_HALF(0, 1, smem);
    STAGE_B_HALF(0, 1, smem + 32768);
    STAGE_A_HALF(1, 0, smem + 65536);
    STAGE_B_HALF(1, 0, smem + 65536 + 32768);

    f32x16 acc[4][2];
    #pragma unroll
    for (int i = 0; i < 4; ++i)
        #pragma unroll
        for (int j = 0; j < 2; ++j)
            #pragma unroll
            for (int e = 0; e < 16; ++e) acc[i][j][e] = 0.f;

    // frag reads: 4 per group, covering (mi in {B,B+1}) x (ks in {2H,2H+1})
    #define READ_A(dst, MIB, H)                                                  \
        _Pragma("unroll")                                                        \
        for (int j = 0; j < 4; ++j) {                                            \
            int mi = (MIB) + (j >> 1), ks = (H) * 2 + (j & 1);                   \
            dst[j] = *(const bf16x8*)(bufA + ks * 8192 + (wr * 4 + mi) * 1024 + lane * 16); \
        }
    #define READ_B(dst, H)                                                       \
        _Pragma("unroll")                                                        \
        for (int j = 0; j < 4; ++j) {                                            \
            int ni = j >> 1, ks = (H) * 2 + (j & 1);                             \
            dst[j] = *(const bf16x8*)(bufB + ks * 8192 + (wc * 2 + ni) * 1024 + lane * 16); \
        }
    #define MFMA8(AOFF, Aset, Bset)                                              \
        __builtin_amdgcn_s_setprio(1);                                           \
        _Pragma("unroll")                                                        \
        for (int mr = 0; mr < 2; ++mr)                                           \
            _Pragma("unroll")                                                    \
            for (int ni = 0; ni < 2; ++ni)                                       \
                _Pragma("unroll")                                                \
                for (int kr = 0; kr < 2; ++kr)                                   \
                    acc[(AOFF) + mr][ni] = __builtin_amdgcn_mfma_f32_32x32x16_bf16( \
                        Aset[mr * 2 + kr], Bset[ni * 2 + kr], acc[(AOFF) + mr][ni], 0, 0, 0); \
        __builtin_amdgcn_s_setprio(0);

    asm volatile("s_waitcnt vmcnt(8)" ::: "memory");   // t0 H0 landed
    asm volatile("s_barrier" ::: "memory");

    for (int t = 0; t < 64; ++t) {
        char* bufA  = smem + (t & 1) * 65536;
        char* bufB  = bufA + 32768;
        char* nbufA = smem + ((t + 1) & 1) * 65536;
        char* nbufB = nbufA + 32768;
        bf16x8 Af[4], Bf[4];

        // ---- Ph0: reads A(mi0-1)+B, H0; stage (t+1) A-H1
        READ_B(Bf, 0);
        READ_A(Af, 0, 0);
        if (t + 1 < 64) STAGE_A_HALF(t + 1, 1, nbufA);
        asm volatile("s_barrier" ::: "memory");
        asm volatile("s_waitcnt lgkmcnt(0)" ::: "memory");
        __builtin_amdgcn_sched_barrier(0);
        MFMA8(0, Af, Bf);
        asm volatile("s_barrier" ::: "memory");

        // ---- Ph1: reads A(mi2-3) H0; stage (t+1) B-H1
        READ_A(Af, 2, 0);
        if (t + 1 < 64) STAGE_B_HALF(t + 1, 1, nbufB);
        asm volatile("s_barrier" ::: "memory");
        asm volatile("s_waitcnt lgkmcnt(0)" ::: "memory");
        __builtin_amdgcn_sched_barrier(0);
        MFMA8(2, Af, Bf);
        if (t < 63) { asm volatile("s_waitcnt vmcnt(8)" ::: "memory"); }  // t H1 landed
        else        { asm volatile("s_waitcnt vmcnt(0)" ::: "memory"); }
        asm volatile("s_barrier" ::: "memory");

        // ---- Ph2: reads A(mi0-1)+B, H1; stage (t+2) A-H0 (H0 reads drained)
        READ_B(Bf, 1);
        READ_A(Af, 0, 1);
        if (t + 2 < 64) STAGE_A_HALF(t + 2, 0, bufA);
        asm volatile("s_barrier" ::: "memory");
        asm volatile("s_waitcnt lgkmcnt(0)" ::: "memory");
        __builtin_amdgcn_sched_barrier(0);
        MFMA8(0, Af, Bf);
        asm volatile("s_barrier" ::: "memory");

        // ---- Ph3: reads A(mi2-3) H1; stage (t+2) B-H0
        READ_A(Af, 2, 1);
        if (t + 2 < 64) STAGE_B_HALF(t + 2, 0, bufB);
        asm volatile("s_barrier" ::: "memory");
        asm volatile("s_waitcnt lgkmcnt(0)" ::: "memory");
        __builtin_amdgcn_sched_barrier(0);
        MFMA8(2, Af, Bf);
        if (t < 62)       { asm volatile("s_waitcnt vmcnt(8)" ::: "memory"); }  // (t+1) H0 landed
        else if (t == 62) { asm volatile("s_waitcnt vmcnt(4)" ::: "memory"); }
        asm volatile("s_barrier" ::: "memory");
    }

    // ---- epilogue: 32x32 C/D mapping col=lane&31, row=(r&3)+8*(r>>2)+4*(lane>>5)
    #pragma unroll
    for (int mi = 0; mi < 4; ++mi) {
        const int mbase = m0 + wr * 128 + mi * 32 + 4 * lhi;   // + (r&3) + 8*(r>>2)
        #pragma unroll
        for (int ni = 0; ni < 2; ++ni) {
            const int dcol = wc * 64 + ni * 32 + l31;
            const float bv = bias[dcol];
            #pragma unroll
            for (int rq = 0; rq < 4; ++rq) {
                float4 zq = *(const float4*)&Z[mbase + rq * 8];
                #pragma unroll
                for (int j = 0; j < 4; ++j) {
                    int node = mbase + rq * 8 + j;
                    float vv = acc[mi][ni][rq * 4 + j] * (1.0f / ((float*)&zq)[j]) + bv;
                    out[((size_t)by * NN + node) * DOUT + dcol] = fmaxf(vv, 0.f);
                }
            }
        }
    }
    #undef STAGE_A_HALF
    #undef STAGE_B_HALF
    #undef READ_A
    #undef READ_B
    #undef MFMA8
}

extern "C" void kernel_launch(void* const* d_in, const int* in_sizes, int n_in,
                              void* d_out, int out_size, void* d_ws, size_t ws_size,
                              hipStream_t stream) {
    const float* x    = (const float*)d_in[0];
    const int*   ids  = (const int*)d_in[1];
    const float* emb  = (const float*)d_in[2];
    const float* W    = (const float*)d_in[3];
    const float* bias = (const float*)d_in[4];
    float* out = (float*)d_out;

    // workspace layout (97.1 MiB total, unchanged footprint)
    char* ws = (char*)d_ws;
    unsigned short* Pbf = (unsigned short*)ws;                            // 32 MiB
    unsigned short* Ebf = (unsigned short*)(ws + 33554432);               // 512 KiB
    float*          Z   = (float*)(ws + 33554432 + 524288);               // 16 KiB
    unsigned short* WT  = (unsigned short*)(ws + 33554432 + 1048576);     // 128 KiB
    unsigned short* yT  = (unsigned short*)(ws + 33554432 + 1048576 + 131072); // 64 MiB

    k_gather <<<NN, ED, 0, stream>>>(emb, ids, Ebf, Z);
    k_logits <<<dim3(NN / 128, NN / 128), 256, 0, stream>>>(Ebf, Pbf, Z);
    k_wt     <<<DOUT, DIN, 0, stream>>>(W, WT);
    k_y      <<<dim3(DOUT / 128, NN / 128, NB), 256, 0, stream>>>(WT, x, yT);
    k_gcn    <<<dim3(16, 32), 512, 0, stream>>>(Pbf, yT, bias, Z, out);
}

// Round 17
// 301.790 us; speedup vs baseline: 1.2230x; 1.2230x over previous
//
#include <hip/hip_runtime.h>

#define NN   4096   // nodes
#define ED   64     // embed dim
#define DIN  256    // in_dim
#define DOUT 256    // out_dim
#define NB   32     // batch

typedef __attribute__((ext_vector_type(8)))  short bf16x8;
typedef __attribute__((ext_vector_type(4)))  float f32x4;

__device__ __forceinline__ unsigned short f2bf(float f) {
    union { float f; unsigned u; } v; v.f = f;
    unsigned r = v.u + 0x7FFF + ((v.u >> 16) & 1);   // round-to-nearest-even
    return (unsigned short)(r >> 16);
}
__device__ __forceinline__ float bf2f(unsigned short s) {
    union { unsigned u; float f; } v; v.u = ((unsigned)s) << 16;
    return v.f;
}

// async global->LDS, 16B per lane; lds dst must be wave-uniform (lane*16 implicit)
#define GLDS16(g, l) __builtin_amdgcn_global_load_lds( \
    (const __attribute__((address_space(1))) void*)(g), \
    (__attribute__((address_space(3))) void*)(l), 16, 0, 0)

// ---------------- K1: Ebf = bf16(emb[node_ids]); Z = 0 ----------------
__global__ void k_gather(const float* __restrict__ emb, const int* __restrict__ ids,
                         unsigned short* __restrict__ Ebf, float* __restrict__ Z) {
    int n = blockIdx.x;
    int e = threadIdx.x;          // 64 threads
    int id = ids[n];
    id = id < 0 ? 0 : (id >= NN ? NN - 1 : id);
    Ebf[(size_t)n * ED + e] = f2bf(emb[(size_t)id * ED + e]);
    if (e == 0) Z[n] = 0.0f;      // zero row-sum accumulator every launch
}

// ---------------- K2: P = exp(relu(E E^T)) bf16 via MFMA; Z[row] += row-sums ----
// 128x128 tile/block, 4 waves (2x2), K=64 one-shot. Fragment-order LDS staging
// ([rowblk][ks][1KB], ds_read = base + lane*16, conflict-free by construction).
// R16-measured: cut non-gcn pipeline time 70 -> 26 us.
__global__ __launch_bounds__(256) void k_logits(const unsigned short* __restrict__ Ebf,
                                                unsigned short* __restrict__ P,
                                                float* __restrict__ Z) {
    __shared__ __align__(16) char sm[32768];      // A 16KB + B 16KB
    const int tid = threadIdx.x;
    const int lane = tid & 63, wid = tid >> 6;    // 4 waves
    const int fr = lane & 15, fq = lane >> 4;
    const int wr = wid >> 1, wc = wid & 1;        // wave tile 64x64
    const int rb = blockIdx.x, cb = blockIdx.y;
    const char* Ep = (const char*)Ebf;            // row stride 128 B

    #pragma unroll
    for (int i = 0; i < 2; ++i) {
        int arb = wid * 2 + i;
        #pragma unroll
        for (int ks = 0; ks < 2; ++ks) {
            GLDS16(Ep + (size_t)(rb * 128 + arb * 16 + fr) * 128 + ks * 64 + fq * 16,
                   sm + arb * 2048 + ks * 1024);
            GLDS16(Ep + (size_t)(cb * 128 + arb * 16 + fr) * 128 + ks * 64 + fq * 16,
                   sm + 16384 + arb * 2048 + ks * 1024);
        }
    }
    asm volatile("s_waitcnt vmcnt(0)" ::: "memory");
    __syncthreads();

    bf16x8 Afr[4][2], Bfr[4][2];
    #pragma unroll
    for (int mi = 0; mi < 4; ++mi)
        #pragma unroll
        for (int ks = 0; ks < 2; ++ks) {
            Afr[mi][ks] = *(const bf16x8*)(sm + (wr * 4 + mi) * 2048 + ks * 1024 + lane * 16);
            Bfr[mi][ks] = *(const bf16x8*)(sm + 16384 + (wc * 4 + mi) * 2048 + ks * 1024 + lane * 16);
        }

    f32x4 acc[4][4];
    #pragma unroll
    for (int i = 0; i < 4; ++i)
        #pragma unroll
        for (int j = 0; j < 4; ++j) acc[i][j] = (f32x4){0.f, 0.f, 0.f, 0.f};
    #pragma unroll
    for (int ks = 0; ks < 2; ++ks)
        #pragma unroll
        for (int mi = 0; mi < 4; ++mi)
            #pragma unroll
            for (int ni = 0; ni < 4; ++ni)
                acc[mi][ni] = __builtin_amdgcn_mfma_f32_16x16x32_bf16(
                    Afr[mi][ks], Bfr[ni][ks], acc[mi][ni], 0, 0, 0);

    // exp(relu(.)) -> P bf16; accumulate row sums
    float rs[4][4];
    #pragma unroll
    for (int mi = 0; mi < 4; ++mi)
        #pragma unroll
        for (int r = 0; r < 4; ++r) rs[mi][r] = 0.f;

    #pragma unroll
    for (int mi = 0; mi < 4; ++mi)
        #pragma unroll
        for (int ni = 0; ni < 4; ++ni) {
            int col = cb * 128 + wc * 64 + ni * 16 + fr;
            #pragma unroll
            for (int r = 0; r < 4; ++r) {
                int row = rb * 128 + wr * 64 + mi * 16 + fq * 4 + r;
                float v = __expf(fmaxf(acc[mi][ni][r], 0.f));
                rs[mi][r] += v;
                P[(size_t)row * NN + col] = f2bf(v);
            }
        }
    #pragma unroll
    for (int mi = 0; mi < 4; ++mi)
        #pragma unroll
        for (int r = 0; r < 4; ++r) {
            float s = rs[mi][r];
            #pragma unroll
            for (int off = 1; off < 16; off <<= 1) s += __shfl_xor(s, off);
            if (fr == 0)
                atomicAdd(&Z[rb * 128 + wr * 64 + mi * 16 + fq * 4 + r], s);
        }
}

// ---------------- K3: WT[m][k] = bf16(W[k][m]) ----------------
__global__ void k_wt(const float* __restrict__ W, unsigned short* __restrict__ WT) {
    int m = blockIdx.x;    // dout
    int k = threadIdx.x;   // din
    WT[(size_t)m * DIN + k] = f2bf(W[(size_t)k * DOUT + m]);
}

// ---------------- K4: yT[b][dout][node] = bf16( (x@W)^T ) ----------------
__global__ __launch_bounds__(256) void k_y(const unsigned short* __restrict__ WT,
                                           const float* __restrict__ x,
                                           unsigned short* __restrict__ yT) {
    __shared__ __align__(16) short As[128 * 32];
    __shared__ __align__(16) short Bs[128 * 32];
    const int tid = threadIdx.x;
    const int lane = tid & 63, w = tid >> 6;
    const int wr = (w >> 1) * 64, wc = (w & 1) * 64;
    const int fr = lane & 15, fq = lane >> 4;
    const int m0 = blockIdx.x * 128;   // dout tile
    const int n0 = blockIdx.y * 128;   // node tile
    const int b  = blockIdx.z;
    const float* xb = x + (size_t)b * NN * DIN;
    const int brow = tid >> 1, bh = (tid & 1) * 16;   // B staging: row, k-half

    f32x4 acc[4][4];
    #pragma unroll
    for (int i = 0; i < 4; ++i)
        #pragma unroll
        for (int j = 0; j < 4; ++j) acc[i][j] = (f32x4){0.f, 0.f, 0.f, 0.f};

    for (int k0 = 0; k0 < DIN; k0 += 32) {
        __syncthreads();
        #pragma unroll
        for (int i = 0; i < 2; ++i) {
            int idx = (w * 2 + i) * 512 + lane * 8;
            int row = idx >> 5, kk = idx & 31;
            GLDS16(WT + (size_t)(m0 + row) * DIN + k0 + kk, &As[(w * 2 + i) * 512]);
        }
        float fv[16];
        *(float4*)&fv[0]  = *(const float4*)&xb[(size_t)(n0 + brow) * DIN + k0 + bh + 0];
        *(float4*)&fv[4]  = *(const float4*)&xb[(size_t)(n0 + brow) * DIN + k0 + bh + 4];
        *(float4*)&fv[8]  = *(const float4*)&xb[(size_t)(n0 + brow) * DIN + k0 + bh + 8];
        *(float4*)&fv[12] = *(const float4*)&xb[(size_t)(n0 + brow) * DIN + k0 + bh + 12];
        unsigned u[8];
        #pragma unroll
        for (int j = 0; j < 8; ++j)
            u[j] = (unsigned)f2bf(fv[2 * j]) | ((unsigned)f2bf(fv[2 * j + 1]) << 16);
        *(uint4*)&Bs[brow * 32 + bh]     = make_uint4(u[0], u[1], u[2], u[3]);
        *(uint4*)&Bs[brow * 32 + bh + 8] = make_uint4(u[4], u[5], u[6], u[7]);
        __syncthreads();

        bf16x8 a[4], bb[4];
        #pragma unroll
        for (int mi = 0; mi < 4; ++mi)
            a[mi] = *(const bf16x8*)&As[(wr + mi * 16 + fr) * 32 + fq * 8];
        #pragma unroll
        for (int ni = 0; ni < 4; ++ni)
            bb[ni] = *(const bf16x8*)&Bs[(wc + ni * 16 + fr) * 32 + fq * 8];
        #pragma unroll
        for (int mi = 0; mi < 4; ++mi)
            #pragma unroll
            for (int ni = 0; ni < 4; ++ni)
                acc[mi][ni] = __builtin_amdgcn_mfma_f32_16x16x32_bf16(
                    a[mi], bb[ni], acc[mi][ni], 0, 0, 0);
    }

    unsigned short* yb = yT + (size_t)b * DOUT * NN;
    #pragma unroll
    for (int mi = 0; mi < 4; ++mi)
        #pragma unroll
        for (int ni = 0; ni < 4; ++ni)
            #pragma unroll
            for (int r = 0; r < 4; ++r) {
                int row = m0 + wr + mi * 16 + fq * 4 + r;   // dout
                int col = n0 + wc + ni * 16 + fr;           // node
                yb[(size_t)row * NN + col] = f2bf(acc[mi][ni][r]);
            }
}

// ---------------- K5: big GEMM (R9/R15 structure, 5x-reproduced best) + 1/Z epilogue ----
// C[4096 x 8192] = P[4096 x 4096] @ Y[4096 x 8192], Y^T = yT flat [8192][4096].
// out[b][node][dout] = relu(C[node][b*256+dout] / Z[node] + bias[dout]).
// LDS per buffer: [ks-half][256 rows][64B] for A and B (16KB half-tiles).
// Per tile: 4 phases (16 MFMA each), ds_reads 8/4/8/4, 2 stage-loads/phase,
// counted vmcnt(8) at both half-tile boundaries. Swizzle: chunk ^= (row>>1)&3.
__global__ __launch_bounds__(512, 2) void k_gcn(const unsigned short* __restrict__ adj,
                                                const unsigned short* __restrict__ yT,
                                                const float* __restrict__ bias,
                                                const float* __restrict__ Z,
                                                float* __restrict__ out) {
    __shared__ __align__(16) char smem[131072];   // 2 bufs x (A 32K + B 32K)

    const int tid  = threadIdx.x;
    const int lane = tid & 63, wid = tid >> 6;    // 8 waves
    const int fr = lane & 15, fq = lane >> 4;
    const int wr = wid >> 2, wc = wid & 3;        // 2 M-waves x 4 N-waves
    const int m0 = blockIdx.x * 256;              // node tile base
    const int by = blockIdx.y;                    // batch

    const char* Apanel = (const char*)(adj + (size_t)m0 * NN);          // row stride 8192 B
    const char* Bpanel = (const char*)(yT + (size_t)by * DOUT * NN);    // rows = dout 0..255

    // stage one 16KB K-half (256 rows x 32k bf16) as 2 gload_lds calls; linear LDS
    // dest, source chunk pre-swizzled with the read-side involution c ^= (r>>1)&3
    #define STAGE_HALF(gpan, ktb, KS, ldsb)                                      \
        { _Pragma("unroll")                                                      \
          for (int h = 0; h < 2; ++h) {                                          \
              int r = h * 128 + wid * 16 + (lane >> 2);                          \
              int gcol = (((lane & 3) ^ ((r >> 1) & 3)) << 4);                   \
              GLDS16((gpan) + (size_t)r * 8192 + (ktb) + (KS) * 64 + gcol,       \
                     (ldsb) + (KS) * 16384 + h * 8192 + wid * 1024);             \
          } }

    // prologue: t0 both halves + t1 ks0 (12 loads, FIFO matches steady state)
    STAGE_HALF(Apanel, 0,   0, smem);
    STAGE_HALF(Bpanel, 0,   0, smem + 32768);
    STAGE_HALF(Apanel, 0,   1, smem);
    STAGE_HALF(Bpanel, 0,   1, smem + 32768);
    STAGE_HALF(Apanel, 128, 0, smem + 65536);
    STAGE_HALF(Bpanel, 128, 0, smem + 65536 + 32768);

    f32x4 acc[8][4];
    #pragma unroll
    for (int i = 0; i < 8; ++i)
        #pragma unroll
        for (int j = 0; j < 4; ++j) acc[i][j] = (f32x4){0.f, 0.f, 0.f, 0.f};

    // per-lane read bases: logical (row, chunk fq) -> L = KS*16384 + row*64 +
    // ((fq ^ ((row>>1)&3))<<4); (row>>1)&3 == (fr>>1)&3 since rowbase%8==0
    const int chunksw = ((fq ^ ((fr >> 1) & 3)) << 4);
    const int arow = (wr * 128 + fr) * 64 + chunksw;   // + rb*1024 + KS*16384
    const int brow = (wc * 64  + fr) * 64 + chunksw;   // + ni*1024 + KS*16384

    #define READ_A(dst, RB0, KS)                                                 \
        _Pragma("unroll")                                                        \
        for (int mi = 0; mi < 4; ++mi)                                           \
            dst[mi] = *(const bf16x8*)(bufA + (KS) * 16384 + arow + ((RB0) + mi) * 1024);
    #define READ_B(dst, KS)                                                      \
        _Pragma("unroll")                                                        \
        for (int ni = 0; ni < 4; ++ni)                                           \
            dst[ni] = *(const bf16x8*)(bufB + (KS) * 16384 + brow + ni * 1024);
    #define MFMA16(AOFF, Aset, Bset)                                             \
        __builtin_amdgcn_s_setprio(1);                                           \
        _Pragma("unroll")                                                        \
        for (int mi = 0; mi < 4; ++mi)                                           \
            _Pragma("unroll")                                                    \
            for (int ni = 0; ni < 4; ++ni)                                       \
                acc[(AOFF) + mi][ni] = __builtin_amdgcn_mfma_f32_16x16x32_bf16(  \
                    Aset[mi], Bset[ni], acc[(AOFF) + mi][ni], 0, 0, 0);          \
        __builtin_amdgcn_s_setprio(0);

    asm volatile("s_waitcnt vmcnt(8)" ::: "memory");   // t0 ks0 landed
    asm volatile("s_barrier" ::: "memory");

    for (int t = 0; t < 64; ++t) {
        char* bufA  = smem + (t & 1) * 65536;
        char* bufB  = bufA + 32768;
        char* nbufA = smem + ((t + 1) & 1) * 65536;
        char* nbufB = nbufA + 32768;
        bf16x8 Af[4], Bf[4];

        // ---- Ph0: reads A(rb0-3) + B (ks0); stage (t+1) A-ks1
        READ_B(Bf, 0);
        READ_A(Af, 0, 0);
        if (t + 1 < 64) STAGE_HALF(Apanel, (t + 1) * 128, 1, nbufA);
        asm volatile("s_barrier" ::: "memory");
        asm volatile("s_waitcnt lgkmcnt(0)" ::: "memory");
        __builtin_amdgcn_sched_barrier(0);
        MFMA16(0, Af, Bf);
        asm volatile("s_barrier" ::: "memory");

        // ---- Ph1: reads A(rb4-7) ks0; stage (t+1) B-ks1
        READ_A(Af, 4, 0);
        if (t + 1 < 64) STAGE_HALF(Bpanel, (t + 1) * 128, 1, nbufB);
        asm volatile("s_barrier" ::: "memory");
        asm volatile("s_waitcnt lgkmcnt(0)" ::: "memory");
        __builtin_amdgcn_sched_barrier(0);
        MFMA16(4, Af, Bf);
        if (t < 63) { asm volatile("s_waitcnt vmcnt(8)" ::: "memory"); }  // t ks1 landed
        else        { asm volatile("s_waitcnt vmcnt(0)" ::: "memory"); }
        asm volatile("s_barrier" ::: "memory");

        // ---- Ph2: reads A(rb0-3) + B (ks1); stage (t+2) A-ks0 (ks0 reads drained)
        READ_B(Bf, 1);
        READ_A(Af, 0, 1);
        if (t + 2 < 64) STAGE_HALF(Apanel, (t + 2) * 128, 0, bufA);
        asm volatile("s_barrier" ::: "memory");
        asm volatile("s_waitcnt lgkmcnt(0)" ::: "memory");
        __builtin_amdgcn_sched_barrier(0);
        MFMA16(0, Af, Bf);
        asm volatile("s_barrier" ::: "memory");

        // ---- Ph3: reads A(rb4-7) ks1; stage (t+2) B-ks0
        READ_A(Af, 4, 1);
        if (t + 2 < 64) STAGE_HALF(Bpanel, (t + 2) * 128, 0, bufB);
        asm volatile("s_barrier" ::: "memory");
        asm volatile("s_waitcnt lgkmcnt(0)" ::: "memory");
        __builtin_amdgcn_sched_barrier(0);
        MFMA16(4, Af, Bf);
        if (t < 62)       { asm volatile("s_waitcnt vmcnt(8)" ::: "memory"); }  // (t+1) ks0 landed
        else if (t == 62) { asm volatile("s_waitcnt vmcnt(4)" ::: "memory"); }
        asm volatile("s_barrier" ::: "memory");
    }

    // ---- epilogue: scale by 1/Z[node], + bias, relu, scatter to out ----
    float bv[4];
    #pragma unroll
    for (int ni = 0; ni < 4; ++ni) bv[ni] = bias[wc * 64 + ni * 16 + fr];

    #pragma unroll
    for (int am = 0; am < 8; ++am) {
        const int node = m0 + wr * 128 + am * 16 + fq * 4;
        float4 zq = *(const float4*)&Z[node];
        float iz[4] = {1.0f / zq.x, 1.0f / zq.y, 1.0f / zq.z, 1.0f / zq.w};
        #pragma unroll
        for (int ni = 0; ni < 4; ++ni) {
            const int dcol = wc * 64 + ni * 16 + fr;
            #pragma unroll
            for (int rr = 0; rr < 4; ++rr) {
                float vv = acc[am][ni][rr] * iz[rr] + bv[ni];
                out[((size_t)by * NN + node + rr) * DOUT + dcol] = fmaxf(vv, 0.f);
            }
        }
    }
    #undef STAGE_HALF
    #undef READ_A
    #undef READ_B
    #undef MFMA16
}

extern "C" void kernel_launch(void* const* d_in, const int* in_sizes, int n_in,
                              void* d_out, int out_size, void* d_ws, size_t ws_size,
                              hipStream_t stream) {
    const float* x    = (const float*)d_in[0];
    const int*   ids  = (const int*)d_in[1];
    const float* emb  = (const float*)d_in[2];
    const float* W    = (const float*)d_in[3];
    const float* bias = (const float*)d_in[4];
    float* out = (float*)d_out;

    // workspace layout (97.1 MiB total, unchanged footprint)
    char* ws = (char*)d_ws;
    unsigned short* Pbf = (unsigned short*)ws;                            // 32 MiB
    unsigned short* Ebf = (unsigned short*)(ws + 33554432);               // 512 KiB
    float*          Z   = (float*)(ws + 33554432 + 524288);               // 16 KiB
    unsigned short* WT  = (unsigned short*)(ws + 33554432 + 1048576);     // 128 KiB
    unsigned short* yT  = (unsigned short*)(ws + 33554432 + 1048576 + 131072); // 64 MiB

    k_gather <<<NN, ED, 0, stream>>>(emb, ids, Ebf, Z);
    k_logits <<<dim3(NN / 128, NN / 128), 256, 0, stream>>>(Ebf, Pbf, Z);
    k_wt     <<<DOUT, DIN, 0, stream>>>(W, WT);
    k_y      <<<dim3(DOUT / 128, NN / 128, NB), 256, 0, stream>>>(WT, x, yT);
    k_gcn    <<<dim3(16, 32), 512, 0, stream>>>(Pbf, yT, bias, Z, out);
}